// Round 4
// baseline (648.393 us; speedup 1.0000x reference)
//
#include <hip/hip_runtime.h>
#include <hip/hip_bf16.h>
#include <stdint.h>

// Problem dims (fixed by harness)
#define Bb 256
#define Nn 196
#define Dd 384
#define Hh 1536
#define NPAD 224      // patch-dim K padded to 7*32 for MFMA
#define MPAD 256      // Wq row pad to 2*128 tiles
#define TTOT (Bb*Nn)  // 50176 tokens
#define XLD 232       // padded LDS stride for Xs (224+8): breaks bank aliasing
#define TK 64         // tokens per mlp block (50176/64 = 784 blocks exactly)
#define HS 256        // hidden slice per pass (1536/256 = 6 passes)

typedef __attribute__((ext_vector_type(8))) __bf16 bf16x8;
typedef __attribute__((ext_vector_type(4))) float f32x4;

// async global->LDS, 16B per lane. LDS dest must be wave-uniform base + lane*16.
#define GLD16(gp, lp) __builtin_amdgcn_global_load_lds( \
    (const __attribute__((address_space(1))) void*)(gp), \
    (__attribute__((address_space(3))) void*)(lp), 16, 0, 0)

__device__ __forceinline__ ushort f2bf(float f){
  union { float f; unsigned u; } v; v.f = f;
  unsigned r = v.u + 0x7FFFu + ((v.u >> 16) & 1u);   // RNE f32->bf16
  return (ushort)(r >> 16);
}

// ---------- absmax over the three weight tensors in one launch (y = tensor id) ----------
__global__ void absmax3_k(const float* __restrict__ wa, const float* __restrict__ w1,
                          const float* __restrict__ w2, unsigned* __restrict__ out){
  int which = blockIdx.y;
  const float* w = which == 0 ? wa : (which == 1 ? w1 : w2);
  int n = which == 0 ? Nn*Nn : Hh*Dd;
  float m = 0.f;
  for (int i = blockIdx.x*blockDim.x + threadIdx.x; i < n; i += gridDim.x*blockDim.x)
    m = fmaxf(m, fabsf(w[i]));
  #pragma unroll
  for (int o = 32; o >= 1; o >>= 1) m = fmaxf(m, __shfl_xor(m, o));
  __shared__ float sm[4];
  if ((threadIdx.x & 63) == 0) sm[threadIdx.x >> 6] = m;
  __syncthreads();
  if (threadIdx.x == 0){
    float mm = fmaxf(fmaxf(sm[0], sm[1]), fmaxf(sm[2], sm[3]));
    atomicMax(out + which, __float_as_uint(mm));   // floats >=0: uint order == float order
  }
}

// ---------- fake-quant W_attn into zero-padded bf16 [MPAD][NPAD] ----------
__global__ void quant_attn_k(const float* __restrict__ W, const unsigned* __restrict__ amax,
                             const int* __restrict__ bitsp, ushort* __restrict__ Wq){
  int idx = blockIdx.x*256 + threadIdx.x;      // grid covers MPAD*NPAD exactly
  int m = idx / NPAD, n = idx - m*NPAD;
  float qmax = (float)((1 << (bitsp[0]-1)) - 1);
  float s = fmaxf(__uint_as_float(amax[0]) / qmax, 1e-8f);
  float v = 0.f;
  if (m < Nn && n < Nn){
    float q = fminf(fmaxf(rintf(W[m*Nn + n] / s), -qmax), qmax);  // rintf = RNE like jnp.round
    v = q * s;
  }
  Wq[idx] = f2bf(v);
}

// ---------- fake-quant a row-major weight to bf16 (same layout) ----------
__global__ void quant_k(const float* __restrict__ W, int n, const unsigned* __restrict__ amax,
                        const int* __restrict__ bitsp, ushort* __restrict__ Wq){
  int idx = blockIdx.x*256 + threadIdx.x;
  if (idx >= n) return;
  float qmax = (float)((1 << (bitsp[0]-1)) - 1);
  float s = fmaxf(__uint_as_float(amax[0]) / qmax, 1e-8f);
  float q = fminf(fmaxf(rintf(W[idx] / s), -qmax), qmax);
  Wq[idx] = f2bf(q * s);
}

// ---------- stage a 128x32 bf16 tile into linear LDS [128][32] via global_load_lds ----------
__device__ __forceinline__ void stage_tile(const ushort* __restrict__ src, long ld, int k0,
                                           ushort* dst){
  const int tid = threadIdx.x;
  const long row = tid >> 2;
  const int  c8  = (tid & 3) * 8;
  GLD16(src + row*ld + k0 + c8,        dst + tid*8);          // rows 0..63
  GLD16(src + (row+64)*ld + k0 + c8,   dst + 2048 + tid*8);   // rows 64..127
}

// ---------- GEMM1 fused: norm1 + transpose + token-mix + layerscale/residual + norm2 ----------
__global__ __launch_bounds__(256) void gemm1_k(const ushort* __restrict__ Wq,
    const float* __restrict__ x,
    const float* __restrict__ alpha1, const float* __restrict__ beta1,
    const float* __restrict__ b_attn, const float* __restrict__ gamma1,
    const float* __restrict__ alpha2, const float* __restrict__ beta2,
    float* __restrict__ x1, ushort* __restrict__ hn2){
  __shared__ ushort Xs[128*XLD];     // 59392 B
  __shared__ ushort BufAs[8192];     // 16 KB: f32 staging buf, then reused as 8 KB As
  const int tid = threadIdx.x;
  const int b = blockIdx.y, dt = blockIdx.x, d0 = dt*128;

  // ---- build Xs: per pass, 32 n-rows of x[b][n][d0:d0+128] -> normed bf16 transposed ----
  {
    float* buf = (float*)BufAs;      // [32][128] f32, linear (gl_lds needs no padding)
    const int dme = tid & 127;
    const float a1 = alpha1[d0 + dme], be1 = beta1[d0 + dme];
    for (int p = 0; p < 7; p++){
      __syncthreads();
      #pragma unroll
      for (int c = 0; c < 4; c++){
        int nn = p*32 + c*8 + (tid >> 5);
        int ncl = nn < Nn ? nn : Nn - 1;          // clamp (no OOB); zeroed at transpose
        GLD16(x + ((long)b*Nn + ncl)*Dd + d0 + (tid & 31)*4,
              (char*)BufAs + c*4096 + tid*16);
      }
      __syncthreads();
      for (int g = tid >> 7; g < 4; g += 2){      // each thread: 2 groups of 8 n
        int n0 = g*8;
        ushort o[8];
        #pragma unroll
        for (int t = 0; t < 8; t++){
          int na = p*32 + n0 + t;
          float val = (na < Nn) ? fmaf(a1, buf[(n0 + t)*128 + dme], be1) : 0.f;
          o[t] = f2bf(val);
        }
        *(int4*)&Xs[dme*XLD + p*32 + n0] = *(int4*)o;
      }
    }
  }

  // ---- 2 M-tiles of 128 over Wq rows; B = persistent Xs ----
  const int lane = tid & 63;
  const int wr = (tid >> 7) & 1, wc = (tid >> 6) & 1;
  const int arow = lane & 15, koff = (lane >> 4)*8;
  ushort* As = BufAs;                // 8 KB reuse
  for (int mt = 0; mt < 2; mt++){
    f32x4 acc[4][4] = {};
    const ushort* Wt = Wq + (long)mt*128*NPAD;
    for (int k0 = 0; k0 < NPAD; k0 += 32){
      __syncthreads();
      stage_tile(Wt, NPAD, k0, As);
      __syncthreads();
      bf16x8 ag[4], bg[4];
      #pragma unroll
      for (int i=0;i<4;i++){
        ag[i] = *(const bf16x8*)&As[(wr*64 + i*16 + arow)*32 + koff];
        bg[i] = *(const bf16x8*)&Xs[(wc*64 + i*16 + arow)*XLD + k0 + koff];
      }
      #pragma unroll
      for (int i=0;i<4;i++)
        #pragma unroll
        for (int j=0;j<4;j++)
          acc[i][j] = __builtin_amdgcn_mfma_f32_16x16x32_bf16(ag[i], bg[j], acc[i][j], 0, 0, 0);
    }
    // epilogue for this M-tile
    #pragma unroll
    for (int i=0;i<4;i++){
      #pragma unroll
      for (int j=0;j<4;j++){
        int d = d0 + wc*64 + j*16 + (lane & 15);
        float g1 = gamma1[d], a2 = alpha2[d], b2v = beta2[d];
        #pragma unroll
        for (int r=0;r<4;r++){
          int m = mt*128 + wr*64 + i*16 + (lane >> 4)*4 + r;
          if (m < Nn){
            long idx = ((long)b*Nn + m)*Dd + d;
            float o = fmaf(g1, acc[i][j][r] + b_attn[m], x[idx]);  // x re-read: L2-warm
            x1[idx]  = o;
            hn2[idx] = f2bf(fmaf(a2, o, b2v));
          }
        }
      }
    }
  }
}

// ---------- fused MLP: out = gamma2*(gelu(hn2@W1^T+b1)@W2^T + b2) + x1  ----------
// Block = 64 tokens; 6 hidden slices of HS=256; hidden P lives in LDS only.
// GEMM-a: 64x256 (wave: 64tok x 64h, 4x4 frags = 16 MFMA/kstep, K=384)
// GEMM-b: 64x384 (wave: 64tok x 96d, 4x6 frags = 24 MFMA/kstep, K=256/slice)
__global__ __launch_bounds__(256) void mlp_k(const ushort* __restrict__ hn2,
    const ushort* __restrict__ W1q, const ushort* __restrict__ W2q,
    const float* __restrict__ b1, const float* __restrict__ b2,
    const float* __restrict__ gamma2, float* __restrict__ out){
  __shared__ ushort U[12288];        // 24 KB union: {As 4K + W1s 16K} | {W2s 24K}
  __shared__ ushort Ps[TK*HS];       // 32 KB: gelu(h) slice, XOR-swizzled rows
  ushort* As  = U;                   // [64][32]
  ushort* W1s = U + 2048;            // [256][32]
  ushort* W2s = U;                   // [384][32]
  const int tid  = threadIdx.x;
  const int lane = tid & 63;
  const int wv   = tid >> 6;           // 0..3
  const int arow = lane & 15;
  const int koff = (lane >> 4) * 8;
  const long t0  = (long)blockIdx.x * TK;
  const int  c8  = (tid & 3) * 8;
  const int  srow = tid >> 2;          // 0..63

  f32x4 oacc[4][6] = {};

  for (int hs = 0; hs < 6; hs++){
    // ---- GEMM-a: P[64 tok][256 h] = hn2_tile @ W1_slice^T, K = 384 ----
    f32x4 pacc[4][4] = {};
    for (int k0 = 0; k0 < Dd; k0 += 32){
      __syncthreads();
      GLD16(hn2 + (t0 + srow)*Dd + k0 + c8, As + tid*8);              // [64][32]
      #pragma unroll
      for (int q=0;q<4;q++)                                           // W1 [256][32]
        GLD16(W1q + (long)(hs*HS + q*64 + srow)*Dd + k0 + c8, W1s + q*2048 + tid*8);
      __syncthreads();
      bf16x8 ag[4], bg[4];
      #pragma unroll
      for (int i=0;i<4;i++) ag[i] = *(const bf16x8*)&As[(i*16 + arow)*32 + koff];
      #pragma unroll
      for (int j=0;j<4;j++) bg[j] = *(const bf16x8*)&W1s[(wv*64 + j*16 + arow)*32 + koff];
      #pragma unroll
      for (int i=0;i<4;i++)
        #pragma unroll
        for (int j=0;j<4;j++)
          pacc[i][j] = __builtin_amdgcn_mfma_f32_16x16x32_bf16(ag[i], bg[j], pacc[i][j], 0, 0, 0);
    }
    // ---- bias + gelu -> Ps (bf16, XOR-swizzled: idx = row*HS + (h ^ ((row&7)<<3))) ----
    {
      #pragma unroll
      for (int i=0;i<4;i++){
        #pragma unroll
        for (int j=0;j<4;j++){
          int hcol = wv*64 + j*16 + (lane & 15);
          float b1v = b1[hs*HS + hcol];
          #pragma unroll
          for (int r=0;r<4;r++){
            int row = i*16 + (lane >> 4)*4 + r;
            float v = pacc[i][j][r] + b1v;
            // jax.nn.gelu approximate: v * sigmoid(1.5957691*(v + 0.044715 v^3))
            float u = 0.7978845608028654f * v * fmaf(0.044715f, v*v, 1.f);
            float g = v / (1.f + __expf(-2.f*u));
            Ps[row*HS + (hcol ^ ((row & 7) << 3))] = f2bf(g);
          }
        }
      }
    }
    // ---- GEMM-b: oacc[64 tok][384 d] += gelu_P @ W2_slice^T, K = 256 ----
    for (int k0 = 0; k0 < HS; k0 += 32){
      __syncthreads();                     // U free (W1/As reads done) + Ps complete
      #pragma unroll
      for (int q=0;q<6;q++)                // W2 [384][32] for this k-step
        GLD16(W2q + (long)(q*64 + srow)*Hh + hs*HS + k0 + c8, W2s + q*2048 + tid*8);
      __syncthreads();
      bf16x8 pa[4], bg[6];
      #pragma unroll
      for (int i=0;i<4;i++){
        int row = i*16 + arow;
        pa[i] = *(const bf16x8*)&Ps[row*HS + ((k0 + koff) ^ ((row & 7) << 3))];
      }
      #pragma unroll
      for (int j=0;j<6;j++) bg[j] = *(const bf16x8*)&W2s[(wv*96 + j*16 + arow)*32 + koff];
      #pragma unroll
      for (int i=0;i<4;i++)
        #pragma unroll
        for (int j=0;j<6;j++)
          oacc[i][j] = __builtin_amdgcn_mfma_f32_16x16x32_bf16(pa[i], bg[j], oacc[i][j], 0, 0, 0);
    }
  }

  // ---- epilogue: out = gamma2*(oacc + b2) + x1 (x1 staged in out) ----
  #pragma unroll
  for (int i=0;i<4;i++){
    #pragma unroll
    for (int j=0;j<6;j++){
      int d = wv*96 + j*16 + (lane & 15);
      float g2 = gamma2[d], b2v = b2[d];
      #pragma unroll
      for (int r=0;r<4;r++){
        long t = t0 + i*16 + (lane >> 4)*4 + r;
        long idx = t*Dd + d;
        out[idx] = fmaf(g2, oacc[i][j][r] + b2v, out[idx]);
      }
    }
  }
}

extern "C" void kernel_launch(void* const* d_in, const int* in_sizes, int n_in,
                              void* d_out, int out_size, void* d_ws, size_t ws_size,
                              hipStream_t stream){
  const float* x      = (const float*)d_in[0];
  const float* alpha1 = (const float*)d_in[1];
  const float* beta1  = (const float*)d_in[2];
  const float* W_attn = (const float*)d_in[3];
  const float* b_attn = (const float*)d_in[4];
  const float* gamma1 = (const float*)d_in[5];
  const float* alpha2 = (const float*)d_in[6];
  const float* beta2  = (const float*)d_in[7];
  const float* W1     = (const float*)d_in[8];
  const float* b1     = (const float*)d_in[9];
  const float* W2     = (const float*)d_in[10];
  const float* b2     = (const float*)d_in[11];
  const float* gamma2 = (const float*)d_in[12];
  const int*   bits   = (const int*)d_in[13];

  // ws layout (256B aligned)
  char* ws = (char*)d_ws;
  unsigned* amax = (unsigned*)ws;                    // [3]
  ushort* Wq   = (ushort*)(ws + 256);                // [256][224] bf16
  ushort* W1q  = (ushort*)(ws + 114944);             // [1536][384]
  ushort* W2q  = (ushort*)(ws + 1294592);            // [384][1536]
  ushort* hn2  = (ushort*)(ws + 2474240);            // [50176][384]
  float*  x1   = (float*)d_out;                      // residual staged in d_out

  hipMemsetAsync(amax, 0, 256, stream);
  absmax3_k<<<dim3(128, 3), 256, 0, stream>>>(W_attn, W1, W2, amax);
  quant_attn_k<<<(MPAD*NPAD)/256, 256, 0, stream>>>(W_attn, amax, bits, Wq);
  quant_k<<<(Hh*Dd)/256, 256, 0, stream>>>(W1, Hh*Dd, amax + 1, bits, W1q);
  quant_k<<<(Hh*Dd)/256, 256, 0, stream>>>(W2, Hh*Dd, amax + 2, bits, W2q);
  gemm1_k<<<dim3(3, Bb), 256, 0, stream>>>(Wq, x, alpha1, beta1, b_attn, gamma1,
                                           alpha2, beta2, x1, hn2);
  mlp_k<<<TTOT/TK, 256, 0, stream>>>(hn2, W1q, W2q, b1, b2, gamma2, (float*)d_out);
}

// Round 5
// 376.298 us; speedup vs baseline: 1.7231x; 1.7231x over previous
//
#include <hip/hip_runtime.h>
#include <hip/hip_bf16.h>
#include <stdint.h>

// Problem dims (fixed by harness)
#define Bb 256
#define Nn 196
#define Dd 384
#define Hh 1536
#define NPAD 224      // patch-dim K padded to 7*32 for MFMA
#define MPAD 256      // Wq row pad to 2*128 tiles
#define TTOT (Bb*Nn)  // 50176 tokens
#define XLD 232       // padded LDS stride for Xs (224+8): breaks bank aliasing
#define TK 64         // tokens per mlp block (50176/64 = 784 blocks exactly)
#define HS 128        // hidden slice per pass (1536/128 = 12 passes)

typedef __attribute__((ext_vector_type(8))) __bf16 bf16x8;
typedef __attribute__((ext_vector_type(4))) float f32x4;

// async global->LDS, 16B per lane. LDS dest must be wave-uniform base + lane*16.
#define GLD16(gp, lp) __builtin_amdgcn_global_load_lds( \
    (const __attribute__((address_space(1))) void*)(gp), \
    (__attribute__((address_space(3))) void*)(lp), 16, 0, 0)

#define MFMA16(a, b, c) __builtin_amdgcn_mfma_f32_16x16x32_bf16((a), (b), (c), 0, 0, 0)

__device__ __forceinline__ ushort f2bf(float f){
  union { float f; unsigned u; } v; v.f = f;
  unsigned r = v.u + 0x7FFFu + ((v.u >> 16) & 1u);   // RNE f32->bf16
  return (ushort)(r >> 16);
}

// ---------- absmax over the three weight tensors in one launch (y = tensor id) ----------
__global__ void absmax3_k(const float* __restrict__ wa, const float* __restrict__ w1,
                          const float* __restrict__ w2, unsigned* __restrict__ out){
  int which = blockIdx.y;
  const float* w = which == 0 ? wa : (which == 1 ? w1 : w2);
  int n = which == 0 ? Nn*Nn : Hh*Dd;
  float m = 0.f;
  for (int i = blockIdx.x*blockDim.x + threadIdx.x; i < n; i += gridDim.x*blockDim.x)
    m = fmaxf(m, fabsf(w[i]));
  #pragma unroll
  for (int o = 32; o >= 1; o >>= 1) m = fmaxf(m, __shfl_xor(m, o));
  __shared__ float sm[4];
  if ((threadIdx.x & 63) == 0) sm[threadIdx.x >> 6] = m;
  __syncthreads();
  if (threadIdx.x == 0){
    float mm = fmaxf(fmaxf(sm[0], sm[1]), fmaxf(sm[2], sm[3]));
    atomicMax(out + which, __float_as_uint(mm));   // floats >=0: uint order == float order
  }
}

// ---------- fake-quant W_attn into zero-padded bf16 [MPAD][NPAD] ----------
__global__ void quant_attn_k(const float* __restrict__ W, const unsigned* __restrict__ amax,
                             const int* __restrict__ bitsp, ushort* __restrict__ Wq){
  int idx = blockIdx.x*256 + threadIdx.x;      // grid covers MPAD*NPAD exactly
  int m = idx / NPAD, n = idx - m*NPAD;
  float qmax = (float)((1 << (bitsp[0]-1)) - 1);
  float s = fmaxf(__uint_as_float(amax[0]) / qmax, 1e-8f);
  float v = 0.f;
  if (m < Nn && n < Nn){
    float q = fminf(fmaxf(rintf(W[m*Nn + n] / s), -qmax), qmax);  // rintf = RNE like jnp.round
    v = q * s;
  }
  Wq[idx] = f2bf(v);
}

// ---------- fake-quant a row-major weight to bf16 (same layout) ----------
__global__ void quant_k(const float* __restrict__ W, int n, const unsigned* __restrict__ amax,
                        const int* __restrict__ bitsp, ushort* __restrict__ Wq){
  int idx = blockIdx.x*256 + threadIdx.x;
  if (idx >= n) return;
  float qmax = (float)((1 << (bitsp[0]-1)) - 1);
  float s = fmaxf(__uint_as_float(amax[0]) / qmax, 1e-8f);
  float q = fminf(fmaxf(rintf(W[idx] / s), -qmax), qmax);
  Wq[idx] = f2bf(q * s);
}

// ---------- stage a 128x32 bf16 tile into linear LDS [128][32] via global_load_lds ----------
__device__ __forceinline__ void stage_tile(const ushort* __restrict__ src, long ld, int k0,
                                           ushort* dst){
  const int tid = threadIdx.x;
  const long row = tid >> 2;
  const int  c8  = (tid & 3) * 8;
  GLD16(src + row*ld + k0 + c8,        dst + tid*8);          // rows 0..63
  GLD16(src + (row+64)*ld + k0 + c8,   dst + 2048 + tid*8);   // rows 64..127
}

// ---------- GEMM1 fused: norm1 + transpose + token-mix + layerscale/residual + norm2 ----------
__global__ __launch_bounds__(256) void gemm1_k(const ushort* __restrict__ Wq,
    const float* __restrict__ x,
    const float* __restrict__ alpha1, const float* __restrict__ beta1,
    const float* __restrict__ b_attn, const float* __restrict__ gamma1,
    const float* __restrict__ alpha2, const float* __restrict__ beta2,
    float* __restrict__ x1, ushort* __restrict__ hn2){
  __shared__ ushort Xs[128*XLD];     // 59392 B
  __shared__ ushort BufAs[8192];     // 16 KB: f32 staging buf, then reused as 8 KB As
  const int tid = threadIdx.x;
  const int b = blockIdx.y, dt = blockIdx.x, d0 = dt*128;

  // ---- build Xs: per pass, 32 n-rows of x[b][n][d0:d0+128] -> normed bf16 transposed ----
  {
    float* buf = (float*)BufAs;      // [32][128] f32, linear (gl_lds needs no padding)
    const int dme = tid & 127;
    const float a1 = alpha1[d0 + dme], be1 = beta1[d0 + dme];
    for (int p = 0; p < 7; p++){
      __syncthreads();
      #pragma unroll
      for (int c = 0; c < 4; c++){
        int nn = p*32 + c*8 + (tid >> 5);
        int ncl = nn < Nn ? nn : Nn - 1;          // clamp (no OOB); zeroed at transpose
        GLD16(x + ((long)b*Nn + ncl)*Dd + d0 + (tid & 31)*4,
              (char*)BufAs + c*4096 + tid*16);
      }
      __syncthreads();
      for (int g = tid >> 7; g < 4; g += 2){      // each thread: 2 groups of 8 n
        int n0 = g*8;
        ushort o[8];
        #pragma unroll
        for (int t = 0; t < 8; t++){
          int na = p*32 + n0 + t;
          float val = (na < Nn) ? fmaf(a1, buf[(n0 + t)*128 + dme], be1) : 0.f;
          o[t] = f2bf(val);
        }
        *(int4*)&Xs[dme*XLD + p*32 + n0] = *(int4*)o;
      }
    }
  }

  // ---- 2 M-tiles of 128 over Wq rows; B = persistent Xs ----
  const int lane = tid & 63;
  const int wr = (tid >> 7) & 1, wc = (tid >> 6) & 1;
  const int arow = lane & 15, koff = (lane >> 4)*8;
  ushort* As = BufAs;                // 8 KB reuse
  for (int mt = 0; mt < 2; mt++){
    f32x4 acc[4][4] = {};
    const ushort* Wt = Wq + (long)mt*128*NPAD;
    for (int k0 = 0; k0 < NPAD; k0 += 32){
      __syncthreads();
      stage_tile(Wt, NPAD, k0, As);
      __syncthreads();
      bf16x8 ag[4], bg[4];
      #pragma unroll
      for (int i=0;i<4;i++){
        ag[i] = *(const bf16x8*)&As[(wr*64 + i*16 + arow)*32 + koff];
        bg[i] = *(const bf16x8*)&Xs[(wc*64 + i*16 + arow)*XLD + k0 + koff];
      }
      #pragma unroll
      for (int i=0;i<4;i++)
        #pragma unroll
        for (int j=0;j<4;j++)
          acc[i][j] = MFMA16(ag[i], bg[j], acc[i][j]);
    }
    // epilogue for this M-tile
    #pragma unroll
    for (int i=0;i<4;i++){
      #pragma unroll
      for (int j=0;j<4;j++){
        int d = d0 + wc*64 + j*16 + (lane & 15);
        float g1 = gamma1[d], a2 = alpha2[d], b2v = beta2[d];
        #pragma unroll
        for (int r=0;r<4;r++){
          int m = mt*128 + wr*64 + i*16 + (lane >> 4)*4 + r;
          if (m < Nn){
            long idx = ((long)b*Nn + m)*Dd + d;
            float o = fmaf(g1, acc[i][j][r] + b_attn[m], x[idx]);  // x re-read: L2-warm
            x1[idx]  = o;
            hn2[idx] = f2bf(fmaf(a2, o, b2v));
          }
        }
      }
    }
  }
}

// ================== fused MLP, 2-phase pipelined ==================
// Per hs slice (12 of HS=128): GEMM-a 6 steps BK=64 (16 MFMA/wave), gelu->Ps,
// GEMM-b 4 steps BK=32 (24 MFMA/wave). Next step's tiles staged via
// global_load_lds BEFORE current compute; one barrier/step (drains vmcnt after MFMAs).
// LDS tiles XOR-swizzled via pre-swizzled GLOBAL source (dest stays linear).

// stage As[64][64] (8KB, 2 GLD) + W1s[128][64] (16KB, 4 GLD), 16B-unit swizzle c16^=(row&7)
__device__ __forceinline__ void stage_a(const ushort* __restrict__ hn2, long t0, int k0,
                                        const ushort* __restrict__ W1q, int hs,
                                        ushort* As, ushort* W1s){
  const int tid = threadIdx.x;
  const int w = tid >> 6, lane = tid & 63;
  const int srcc = (((lane & 7) ^ ((lane >> 3) & 7))) * 8;   // swizzled ushort col
  const int rowa = w*8 + (lane >> 3);
  GLD16(hn2 + (t0 + rowa)*Dd + k0 + srcc,        As + (w*64 + lane)*8);
  GLD16(hn2 + (t0 + 32 + rowa)*Dd + k0 + srcc,   As + (256 + w*64 + lane)*8);
  #pragma unroll
  for (int q = 0; q < 4; q++){
    int row = q*32 + rowa;
    GLD16(W1q + ((long)hs*HS + row)*Dd + k0 + srcc, W1s + (q*256 + w*64 + lane)*8);
  }
}

// stage W2s[384][32] (24KB, 6 GLD), 16B-unit swizzle c4 ^= (row>>1)&3
__device__ __forceinline__ void stage_b(const ushort* __restrict__ W2q, int hcol0,
                                        ushort* W2s){
  const int tid = threadIdx.x;
  const int w = tid >> 6, lane = tid & 63;
  const int srcc = ((lane & 3) ^ ((lane >> 3) & 3)) * 8;
  #pragma unroll
  for (int q = 0; q < 6; q++){
    int row = q*64 + w*16 + (lane >> 2);
    GLD16(W2q + (long)row*Hh + hcol0 + srcc, W2s + (q*256 + w*64 + lane)*8);
  }
}

__global__ __launch_bounds__(256, 2) void mlp_k(const ushort* __restrict__ hn2,
    const ushort* __restrict__ W1q, const ushort* __restrict__ W2q,
    const float* __restrict__ b1, const float* __restrict__ b2,
    const float* __restrict__ gamma2, float* __restrict__ out){
  // 72KB: Asb0 8K | Ps 16K (Asb1 aliases its first 8K — disjoint lifetimes) | Wsb 2x24K
  __shared__ ushort SH[36864];
  ushort* const AsP[2] = { SH, SH + 4096 };          // Asb1 aliases Ps[0..4095]
  ushort* const Ps     = SH + 4096;                  // [64][128] swizzled
  ushort* const WsP[2] = { SH + 12288, SH + 24576 }; // W1 uses first 8192 ushorts

  const int tid  = threadIdx.x;
  const int lane = tid & 63;
  const int wv   = tid >> 6;
  const int arow = lane & 15;
  const int g    = lane >> 4;          // 0..3
  const long t0  = (long)blockIdx.x * TK;

  f32x4 oacc[4][6] = {};

  stage_a(hn2, t0, 0, W1q, 0, AsP[0], WsP[0]);
  __syncthreads();

  for (int hs = 0; hs < 12; hs++){
    f32x4 pacc[4][2] = {};
    // ---- GEMM-a: P[64 tok][128 h], 6 steps of BK=64 ----
    #pragma unroll
    for (int ka = 0; ka < 6; ka++){
      const int cur = ka & 1;
      if (ka < 5) stage_a(hn2, t0, (ka+1)*64, W1q, hs, AsP[cur^1], WsP[cur^1]);
      else        stage_b(W2q, hs*HS, WsP[0]);       // b0 loads fly over a5+gelu
      const ushort* As  = AsP[cur];
      const ushort* W1s = WsP[cur];
      bf16x8 ag[4][2], bg[2][2];
      #pragma unroll
      for (int i=0;i<4;i++)
        #pragma unroll
        for (int ks=0;ks<2;ks++)
          ag[i][ks] = *(const bf16x8*)&As[(i*16 + arow)*64 + (((ks*4 + g) ^ (arow & 7))*8)];
      #pragma unroll
      for (int j=0;j<2;j++)
        #pragma unroll
        for (int ks=0;ks<2;ks++)
          bg[j][ks] = *(const bf16x8*)&W1s[(wv*32 + j*16 + arow)*64 + (((ks*4 + g) ^ (arow & 7))*8)];
      #pragma unroll
      for (int ks=0;ks<2;ks++)
        #pragma unroll
        for (int i=0;i<4;i++)
          #pragma unroll
          for (int j=0;j<2;j++)
            pacc[i][j] = MFMA16(ag[i][ks], bg[j][ks], pacc[i][j]);
      __syncthreads();
    }
    // ---- bias + gelu -> Ps (swizzled: idx = row*128 + (h ^ ((row&7)<<3))) ----
    #pragma unroll
    for (int j=0;j<2;j++){
      int hcol = wv*32 + j*16 + arow;
      float b1v = b1[hs*HS + hcol];
      #pragma unroll
      for (int i=0;i<4;i++){
        #pragma unroll
        for (int r=0;r<4;r++){
          int row = i*16 + g*4 + r;
          float v = pacc[i][j][r] + b1v;
          // jax.nn.gelu approximate: v * sigmoid(1.5957691*(v + 0.044715 v^3))
          float u = 0.7978845608028654f * v * fmaf(0.044715f, v*v, 1.f);
          float gl = v / (1.f + __expf(-2.f*u));
          Ps[row*128 + (hcol ^ ((row & 7) << 3))] = f2bf(gl);
        }
      }
    }
    __syncthreads();   // drains b0's W2 loads + makes Ps visible
    // ---- GEMM-b: oacc[64 tok][384 d] += P @ W2_slice^T, 4 steps of BK=32 ----
    #pragma unroll
    for (int kb = 0; kb < 4; kb++){
      const int cur = kb & 1;
      if (kb < 3)       stage_b(W2q, hs*HS + (kb+1)*32, WsP[cur^1]);
      else if (hs < 11) stage_a(hn2, t0, 0, W1q, hs+1, AsP[0], WsP[0]);
      const ushort* W2s = WsP[cur];
      bf16x8 pa[4], bgb[6];
      #pragma unroll
      for (int i=0;i<4;i++){
        int row = i*16 + arow;
        pa[i] = *(const bf16x8*)&Ps[row*128 + ((kb*32 + g*8) ^ ((row & 7) << 3))];
      }
      #pragma unroll
      for (int j=0;j<6;j++){
        int row = wv*96 + j*16 + arow;
        bgb[j] = *(const bf16x8*)&W2s[row*32 + ((g ^ ((arow >> 1) & 3))*8)];
      }
      #pragma unroll
      for (int i=0;i<4;i++)
        #pragma unroll
        for (int j=0;j<6;j++)
          oacc[i][j] = MFMA16(pa[i], bgb[j], oacc[i][j]);
      __syncthreads();
    }
  }

  // ---- epilogue: out = gamma2*(oacc + b2) + x1 (x1 staged in out) ----
  #pragma unroll
  for (int i=0;i<4;i++){
    #pragma unroll
    for (int j=0;j<6;j++){
      int d = wv*96 + j*16 + arow;
      float g2 = gamma2[d], b2v = b2[d];
      #pragma unroll
      for (int r=0;r<4;r++){
        long t = t0 + i*16 + g*4 + r;
        long idx = t*Dd + d;
        out[idx] = fmaf(g2, oacc[i][j][r] + b2v, out[idx]);
      }
    }
  }
}

extern "C" void kernel_launch(void* const* d_in, const int* in_sizes, int n_in,
                              void* d_out, int out_size, void* d_ws, size_t ws_size,
                              hipStream_t stream){
  const float* x      = (const float*)d_in[0];
  const float* alpha1 = (const float*)d_in[1];
  const float* beta1  = (const float*)d_in[2];
  const float* W_attn = (const float*)d_in[3];
  const float* b_attn = (const float*)d_in[4];
  const float* gamma1 = (const float*)d_in[5];
  const float* alpha2 = (const float*)d_in[6];
  const float* beta2  = (const float*)d_in[7];
  const float* W1     = (const float*)d_in[8];
  const float* b1     = (const float*)d_in[9];
  const float* W2     = (const float*)d_in[10];
  const float* b2     = (const float*)d_in[11];
  const float* gamma2 = (const float*)d_in[12];
  const int*   bits   = (const int*)d_in[13];

  // ws layout (256B aligned)
  char* ws = (char*)d_ws;
  unsigned* amax = (unsigned*)ws;                    // [3]
  ushort* Wq   = (ushort*)(ws + 256);                // [256][224] bf16
  ushort* W1q  = (ushort*)(ws + 114944);             // [1536][384]
  ushort* W2q  = (ushort*)(ws + 1294592);            // [384][1536]
  ushort* hn2  = (ushort*)(ws + 2474240);            // [50176][384]
  float*  x1   = (float*)d_out;                      // residual staged in d_out

  hipMemsetAsync(amax, 0, 256, stream);
  absmax3_k<<<dim3(128, 3), 256, 0, stream>>>(W_attn, W1, W2, amax);
  quant_attn_k<<<(MPAD*NPAD)/256, 256, 0, stream>>>(W_attn, amax, bits, Wq);
  quant_k<<<(Hh*Dd)/256, 256, 0, stream>>>(W1, Hh*Dd, amax + 1, bits, W1q);
  quant_k<<<(Hh*Dd)/256, 256, 0, stream>>>(W2, Hh*Dd, amax + 2, bits, W2q);
  gemm1_k<<<dim3(3, Bb), 256, 0, stream>>>(Wq, x, alpha1, beta1, b_attn, gamma1,
                                           alpha2, beta2, x1, hn2);
  mlp_k<<<TTOT/TK, 256, 0, stream>>>(hn2, W1q, W2q, b1, b2, gamma2, (float*)d_out);
}